// Round 6
// baseline (381.130 us; speedup 1.0000x reference)
//
#include <hip/hip_runtime.h>

typedef float v2f  __attribute__((ext_vector_type(2)));
typedef float f32x4 __attribute__((ext_vector_type(4)));
typedef _Float16 h16;
typedef h16 half8 __attribute__((ext_vector_type(8)));

#define NIMG 8
#define XSTR  34                 // x row stride (f32), b64-aligned, <=2-way banks
#define XIMG  (32 * XSTR)        // 1088

// s2: f16 channel-interleaved [img][row14][col14][c8], img stride 197 chunks
#define S2IMGH 1576              // halves per image (197*8)

// ---- LDS layout (f32 units) ----
// R_X [0,8704): phase C1 = x fp32 8x1088.
//   aliased post-C1: c3B h16 [0,1792) | s4f fp32 @1792 (3200) | c5o @4992 (960) | f6 @5952 (672)
// R_S2 [8704,15008): s2 h16 (12608 halves)
// c1w @15008 (192) | c1b @15200 (8) | c3bias @15208 (16)
#define S4F_OFF   1792
#define C5O_OFF   4992
#define F6_OFF    5952
#define S2_OFF32  8704
#define C1W_OFF   15008
#define C1B_OFF   15200
#define C3BIAS_OFF 15208
#define SMEM_F32  15232          // 60,928 B -> 2 blocks/CU

// Inverse connectivity: C3_INV[map][chan] = slot in that map's input list, -1 if absent
__device__ __constant__ int C3_INV[16][6] = {
    {0,1,2,-1,-1,-1},{-1,0,1,2,-1,-1},{-1,-1,0,1,2,-1},{-1,-1,-1,0,1,2},
    {0,-1,-1,-1,1,2},{0,1,-1,-1,-1,2},
    {0,1,2,3,-1,-1},{-1,0,1,2,3,-1},{-1,-1,0,1,2,3},{0,-1,-1,1,2,3},
    {0,1,-1,-1,2,3},{0,1,2,-1,-1,3},{0,1,-1,2,3,-1},{-1,0,1,-1,2,3},
    {0,-1,1,2,-1,3},
    {0,1,2,3,4,5}
};

__device__ __forceinline__ float fast_tanh(float x) {
    float e = __expf(2.0f * x);
    return fmaf(-2.0f, __builtin_amdgcn_rcpf(e + 1.0f), 1.0f);
}
__device__ __forceinline__ v2f fma2(v2f a, v2f b, v2f c) {
    return __builtin_elementwise_fma(a, b, c);
}

__global__ __launch_bounds__(256) void lenet_fused(
    const float* __restrict__ x,
    const float* __restrict__ c1_w,  const float* __restrict__ c1_b,
    const float* __restrict__ c3_w3, const float* __restrict__ c3_b3,
    const float* __restrict__ c3_w4, const float* __restrict__ c3_b4,
    const float* __restrict__ c3_w6, const float* __restrict__ c3_b6,
    const float* __restrict__ c5_w,  const float* __restrict__ c5_b,
    const float* __restrict__ l1_w,  const float* __restrict__ l1_b,
    const float* __restrict__ l2_w,  const float* __restrict__ l2_b,
    float* __restrict__ out, int B)
{
    __shared__ __align__(16) float smem[SMEM_F32];
    float* x_s   = smem;                       // phase C1
    h16*   c3Bh  = (h16*)smem;                 // phase C3 (aliases x)
    float* s4f   = smem + S4F_OFF;             // 8 x 400 fp32, k = ch*25+pos
    float* c5o_s = smem + C5O_OFF;
    float* f6_s  = smem + F6_OFF;
    h16*   s2h   = (h16*)(smem + S2_OFF32);
    float* c1w_s = smem + C1W_OFF;
    float* c1b_s = smem + C1B_OFF;
    float* c3b_s = smem + C3BIAS_OFF;

    const int tid  = threadIdx.x;
    const int img0 = blockIdx.x * NIMG;
    const int nimg = min(NIMG, B - img0);
    if (nimg <= 0) return;

    // ---- prefetch dense C3 MFMA B-panel into 14 regs (stored to LDS post-C1) ----
    // layout: e = t*512 + lane*8 + j; lane: n=map=lane&15, chunk=lane>>4; j = channel c
    // t<=4: dr=chunk, dc=t | t==5: dr=4, dc=chunk | t==6: chunk0 -> (4,4), rest zero
    float c3wr[14];
    #pragma unroll
    for (int u = 0; u < 14; ++u) {
        const int e = tid + 256 * u;
        const int t = e >> 9, rem = e & 511, L = rem >> 3, j = rem & 7;
        const int n = L & 15, chunk = L >> 4, c = j;
        int dr, dc; bool valid = true;
        if (t <= 4)      { dr = chunk; dc = t; }
        else if (t == 5) { dr = 4; dc = chunk; }
        else             { dr = 4; dc = 4; valid = (chunk == 0); }
        float val = 0.0f;
        if (valid && c < 6) {
            const int cc = C3_INV[n][c];
            if (cc >= 0) {
                const int off = dr * 5 + dc;
                if (n < 6)       val = c3_w3[(n * 3 + cc) * 25 + off];
                else if (n < 15) val = c3_w4[((n - 6) * 4 + cc) * 25 + off];
                else             val = c3_w6[cc * 25 + off];
            }
        }
        c3wr[u] = val;
    }

    // ---- stage small weights ----
    if (tid < 192) {
        int c = tid >> 5, r = tid & 31;
        int row = r / 6, v = r % 6;
        c1w_s[tid] = (row < 5 && v < 5) ? c1_w[c * 25 + row * 5 + v] : 0.0f;
    }
    if (tid < 6) c1b_s[tid] = c1_b[tid];
    if (tid < 6)        c3b_s[tid] = c3_b3[tid];
    else if (tid < 15)  c3b_s[tid] = c3_b4[tid - 6];
    else if (tid == 15) c3b_s[15]  = c3_b6[0];

    // ---- zero s2 (channels 6,7 must be 0 for MFMA; also covers missing imgs) ----
    {
        float4 z4 = {0.f, 0.f, 0.f, 0.f};
        float4* zp = (float4*)(smem + S2_OFF32);
        for (int i = tid; i < 1576; i += 256) zp[i] = z4;
    }

    // ---- stage x (fp32) ----
    {
        const float4* xg = (const float4*)(x + (size_t)img0 * 1024);
        const int n4 = nimg * 256;
        for (int i = tid; i < n4; i += 256) {
            float4 v = xg[i];
            int img = i >> 8, q = i & 255;
            int row = q >> 3, col4 = (q & 7) << 2;
            float* p = x_s + img * XIMG + row * XSTR + col4;
            *(float2*)(p)     = (float2){v.x, v.y};
            *(float2*)(p + 2) = (float2){v.z, v.w};
        }
    }
    __syncthreads();

    // ---- C1 (fp32 VALU, round-5 proven) + tanh + pool -> s2 f16 interleaved ----
    for (int it = tid; it < nimg * 168; it += 256) {
        int h   = it & 1;
        int t2  = it >> 1;
        int i   = t2 % 14;
        int t3  = t2 / 14;
        int c   = t3 % 6;
        int img = t3 / 6;
        const float* xb = x_s + img * XIMG + 14 * h;
        const float* wb = c1w_s + c * 32;
        v2f acc2[14];
        #pragma unroll
        for (int j = 0; j < 14; ++j) acc2[j] = (v2f){0.0f, 0.0f};
        float wlo[5], whi[5];
        #pragma unroll
        for (int v = 0; v < 5; ++v) whi[v] = 0.0f;
        #pragma unroll
        for (int xr = 0; xr < 6; ++xr) {
            if (xr <= 4) {
                float2 w0 = *(const float2*)(wb + xr * 6);
                float2 w1 = *(const float2*)(wb + xr * 6 + 2);
                float2 w2 = *(const float2*)(wb + xr * 6 + 4);
                wlo[0] = w0.x; wlo[1] = w0.y; wlo[2] = w1.x; wlo[3] = w1.y; wlo[4] = w2.x;
            } else {
                #pragma unroll
                for (int v = 0; v < 5; ++v) wlo[v] = 0.0f;
            }
            float row[18];
            const float* rp = xb + (2 * i + xr) * XSTR;
            #pragma unroll
            for (int k = 0; k < 9; ++k) {
                float2 t = *(const float2*)(rp + 2 * k);
                row[2 * k] = t.x; row[2 * k + 1] = t.y;
            }
            v2f wp[5];
            #pragma unroll
            for (int v = 0; v < 5; ++v) wp[v] = (v2f){wlo[v], whi[v]};
            #pragma unroll
            for (int j = 0; j < 14; ++j) {
                acc2[j] = fma2((v2f){row[j],     row[j]},     wp[0], acc2[j]);
                acc2[j] = fma2((v2f){row[j + 1], row[j + 1]}, wp[1], acc2[j]);
                acc2[j] = fma2((v2f){row[j + 2], row[j + 2]}, wp[2], acc2[j]);
                acc2[j] = fma2((v2f){row[j + 3], row[j + 3]}, wp[3], acc2[j]);
                acc2[j] = fma2((v2f){row[j + 4], row[j + 4]}, wp[4], acc2[j]);
            }
            #pragma unroll
            for (int v = 0; v < 5; ++v) whi[v] = wlo[v];
        }
        const float b = c1b_s[c];
        h16* o = s2h + img * S2IMGH + (i * 14 + 7 * h) * 8 + c;
        #pragma unroll
        for (int j = 0; j < 7; ++j) {
            float t00 = fast_tanh(acc2[2 * j].x     + b);
            float t01 = fast_tanh(acc2[2 * j + 1].x + b);
            float t10 = fast_tanh(acc2[2 * j].y     + b);
            float t11 = fast_tanh(acc2[2 * j + 1].y + b);
            o[j * 8] = (h16)(0.25f * (t00 + t01 + t10 + t11));
        }
    }
    __syncthreads();

    // ---- x dead: store prefetched C3 MFMA B-panel ----
    #pragma unroll
    for (int u = 0; u < 14; ++u) c3Bh[tid + 256 * u] = (h16)c3wr[u];
    __syncthreads();

    // ---- C3 via MFMA f16: 7 MFMAs per position, pooled quads per wave ----
    {
        const int lane = tid & 63, wv = tid >> 6;
        const int nloc = lane & 15, q4 = lane >> 4;
        half8 bf[7];
        #pragma unroll
        for (int t = 0; t < 7; ++t)
            bf[t] = *(const half8*)(c3Bh + t * 512 + lane * 8);
        const float bias = c3b_s[nloc];
        const int abase = (nloc & 7) * S2IMGH;   // A: m=lane&15 -> image (dup 8..15)
        for (int q = wv; q < 25; q += 4) {
            const int pr = q / 5, pc = q % 5;
            f32x4 acc[2][2];
            #pragma unroll
            for (int a = 0; a < 2; ++a)
                #pragma unroll
                for (int b2 = 0; b2 < 2; ++b2)
                    acc[a][b2] = (f32x4){0.f, 0.f, 0.f, 0.f};
            #pragma unroll
            for (int a = 0; a < 2; ++a) {
                #pragma unroll
                for (int b2 = 0; b2 < 2; ++b2) {
                    const int r = 2 * pr + a, col = 2 * pc + b2;
                    #pragma unroll
                    for (int t = 0; t < 5; ++t) {
                        half8 A = *(const half8*)(s2h + abase + ((r + q4) * 14 + col + t) * 8);
                        acc[a][b2] = __builtin_amdgcn_mfma_f32_16x16x32_f16(A, bf[t], acc[a][b2], 0, 0, 0);
                    }
                    half8 A5 = *(const half8*)(s2h + abase + ((r + 4) * 14 + col + q4) * 8);
                    acc[a][b2] = __builtin_amdgcn_mfma_f32_16x16x32_f16(A5, bf[5], acc[a][b2], 0, 0, 0);
                    half8 A6 = *(const half8*)(s2h + abase + ((r + 4) * 14 + col + 4) * 8);
                    acc[a][b2] = __builtin_amdgcn_mfma_f32_16x16x32_f16(A6, bf[6], acc[a][b2], 0, 0, 0);
                }
            }
            // epilogue: tanh + 2x2 avgpool -> s4f[img][map*25 + pos] fp32
            const int pos = pr * 5 + pc;
            #pragma unroll
            for (int rr = 0; rr < 4; ++rr) {
                const int img = q4 * 4 + rr;       // C/D: row=(lane>>4)*4+reg
                if (img < nimg) {
                    float s = fast_tanh(acc[0][0][rr] + bias) + fast_tanh(acc[0][1][rr] + bias)
                            + fast_tanh(acc[1][0][rr] + bias) + fast_tanh(acc[1][1][rr] + bias);
                    s4f[img * 400 + nloc * 25 + pos] = 0.25f * s;
                }
            }
        }
    }
    __syncthreads();

    // ---- C5: FC 400 -> 120, tanh (VALU, proven) ----
    for (int it = tid; it < nimg * 60; it += 256) {
        int op  = it % 60;
        int img = it / 60;
        int o0  = op * 2;
        const float4* wa = (const float4*)(c5_w + (size_t)o0 * 400);
        const float4* wb = (const float4*)(c5_w + (size_t)o0 * 400 + 400);
        const float4* sv = (const float4*)(s4f + img * 400);
        v2f a2 = (v2f){0.0f, 0.0f}, b2 = (v2f){0.0f, 0.0f};
        #pragma unroll 4
        for (int k = 0; k < 100; ++k) {
            float4 s = sv[k];
            float4 u = wa[k];
            float4 v = wb[k];
            v2f slo = {s.x, s.y}, shi = {s.z, s.w};
            a2 = fma2(slo, (v2f){u.x, u.y}, a2);
            a2 = fma2(shi, (v2f){u.z, u.w}, a2);
            b2 = fma2(slo, (v2f){v.x, v.y}, b2);
            b2 = fma2(shi, (v2f){v.z, v.w}, b2);
        }
        c5o_s[img * 120 + o0]     = fast_tanh(a2.x + a2.y + c5_b[o0]);
        c5o_s[img * 120 + o0 + 1] = fast_tanh(b2.x + b2.y + c5_b[o0 + 1]);
    }
    __syncthreads();

    // ---- F6: FC 120 -> 84, tanh ----
    for (int it = tid; it < nimg * 84; it += 256) {
        int o   = it % 84;
        int img = it / 84;
        const float4* wv = (const float4*)(l1_w + o * 120);
        const float4* cv = (const float4*)(c5o_s + img * 120);
        v2f a2 = (v2f){0.0f, 0.0f};
        #pragma unroll
        for (int k = 0; k < 30; ++k) {
            float4 u = wv[k];
            float4 s = cv[k];
            a2 = fma2((v2f){s.x, s.y}, (v2f){u.x, u.y}, a2);
            a2 = fma2((v2f){s.z, s.w}, (v2f){u.z, u.w}, a2);
        }
        f6_s[img * 84 + o] = fast_tanh(a2.x + a2.y + l1_b[o]);
    }
    __syncthreads();

    // ---- Output: FC 84 -> 10 ----
    for (int it = tid; it < nimg * 10; it += 256) {
        int o   = it % 10;
        int img = it / 10;
        const float4* wv = (const float4*)(l2_w + o * 84);
        const float4* fv = (const float4*)(f6_s + img * 84);
        v2f a2 = (v2f){0.0f, 0.0f};
        #pragma unroll
        for (int k = 0; k < 21; ++k) {
            float4 u = wv[k];
            float4 s = fv[k];
            a2 = fma2((v2f){s.x, s.y}, (v2f){u.x, u.y}, a2);
            a2 = fma2((v2f){s.z, s.w}, (v2f){u.z, u.w}, a2);
        }
        out[(size_t)(img0 + img) * 10 + o] = a2.x + a2.y + l2_b[o];
    }
}

extern "C" void kernel_launch(void* const* d_in, const int* in_sizes, int n_in,
                              void* d_out, int out_size, void* d_ws, size_t ws_size,
                              hipStream_t stream) {
    const float* x     = (const float*)d_in[0];
    const float* c1_w  = (const float*)d_in[1];
    const float* c1_b  = (const float*)d_in[2];
    const float* c3_w3 = (const float*)d_in[3];
    const float* c3_b3 = (const float*)d_in[4];
    const float* c3_w4 = (const float*)d_in[5];
    const float* c3_b4 = (const float*)d_in[6];
    const float* c3_w6 = (const float*)d_in[7];
    const float* c3_b6 = (const float*)d_in[8];
    const float* c5_w  = (const float*)d_in[9];
    const float* c5_b  = (const float*)d_in[10];
    const float* l1_w  = (const float*)d_in[11];
    const float* l1_b  = (const float*)d_in[12];
    const float* l2_w  = (const float*)d_in[13];
    const float* l2_b  = (const float*)d_in[14];
    float* out = (float*)d_out;

    const int B = in_sizes[0] / 1024;   // [B,1,32,32]
    const int grid = (B + NIMG - 1) / NIMG;
    lenet_fused<<<grid, 256, 0, stream>>>(
        x, c1_w, c1_b, c3_w3, c3_b3, c3_w4, c3_b4, c3_w6, c3_b6,
        c5_w, c5_b, l1_w, l1_b, l2_w, l2_b, out, B);
}

// Round 8
// 221.819 us; speedup vs baseline: 1.7182x; 1.7182x over previous
//
#include <hip/hip_runtime.h>

typedef float v2f   __attribute__((ext_vector_type(2)));
typedef float f32x4 __attribute__((ext_vector_type(4)));
typedef _Float16 h16;
typedef h16 half8 __attribute__((ext_vector_type(8)));

__device__ __forceinline__ float fast_tanh(float x) {
    float e = __expf(2.0f * x);
    return fmaf(-2.0f, __builtin_amdgcn_rcpf(e + 1.0f), 1.0f);
}
__device__ __forceinline__ v2f fma2(v2f a, v2f b, v2f c) {
    return __builtin_elementwise_fma(a, b, c);
}

// ============================ K1: C1 + tanh + pool ============================
// 4 img/block, grid B/4. Round-5 proven C1 code; writes s2 f16 c-major
// [img][c][196] to ws. LDS 18.2 KB -> 8 blocks/CU.
#define K1_IMG 4
#define XSTR  34
#define XIMG  (32 * XSTR)        // 1088
#define K1_SMEM (K1_IMG * XIMG + 192 + 8)   // 4552 f32

__global__ __launch_bounds__(256) void k_c1(
    const float* __restrict__ x, const float* __restrict__ c1_w,
    const float* __restrict__ c1_b, h16* __restrict__ s2g, int B)
{
    __shared__ __align__(16) float smem[K1_SMEM];
    float* x_s   = smem;
    float* c1w_s = smem + K1_IMG * XIMG;
    float* c1b_s = c1w_s + 192;

    const int tid  = threadIdx.x;
    const int img0 = blockIdx.x * K1_IMG;
    const int nimg = min(K1_IMG, B - img0);
    if (nimg <= 0) return;

    if (tid < 192) {
        int c = tid >> 5, r = tid & 31;
        int row = r / 6, v = r % 6;
        c1w_s[tid] = (row < 5 && v < 5) ? c1_w[c * 25 + row * 5 + v] : 0.0f;
    }
    if (tid < 6) c1b_s[tid] = c1_b[tid];

    {
        const float4* xg = (const float4*)(x + (size_t)img0 * 1024);
        const int n4 = nimg * 256;
        for (int i = tid; i < n4; i += 256) {
            float4 v = xg[i];
            int img = i >> 8, q = i & 255;
            int row = q >> 3, col4 = (q & 7) << 2;
            float* p = x_s + img * XIMG + row * XSTR + col4;
            *(float2*)(p)     = (float2){v.x, v.y};
            *(float2*)(p + 2) = (float2){v.z, v.w};
        }
    }
    __syncthreads();

    for (int it = tid; it < nimg * 168; it += 256) {
        int h   = it & 1;
        int t2  = it >> 1;
        int i   = t2 % 14;
        int t3  = t2 / 14;
        int c   = t3 % 6;
        int img = t3 / 6;
        const float* xb = x_s + img * XIMG + 14 * h;
        const float* wb = c1w_s + c * 32;
        v2f acc2[14];
        #pragma unroll
        for (int j = 0; j < 14; ++j) acc2[j] = (v2f){0.0f, 0.0f};
        float wlo[5], whi[5];
        #pragma unroll
        for (int v = 0; v < 5; ++v) whi[v] = 0.0f;
        #pragma unroll
        for (int xr = 0; xr < 6; ++xr) {
            if (xr <= 4) {
                float2 w0 = *(const float2*)(wb + xr * 6);
                float2 w1 = *(const float2*)(wb + xr * 6 + 2);
                float2 w2 = *(const float2*)(wb + xr * 6 + 4);
                wlo[0] = w0.x; wlo[1] = w0.y; wlo[2] = w1.x; wlo[3] = w1.y; wlo[4] = w2.x;
            } else {
                #pragma unroll
                for (int v = 0; v < 5; ++v) wlo[v] = 0.0f;
            }
            float row[18];
            const float* rp = xb + (2 * i + xr) * XSTR;
            #pragma unroll
            for (int k = 0; k < 9; ++k) {
                float2 t = *(const float2*)(rp + 2 * k);
                row[2 * k] = t.x; row[2 * k + 1] = t.y;
            }
            v2f wp[5];
            #pragma unroll
            for (int v = 0; v < 5; ++v) wp[v] = (v2f){wlo[v], whi[v]};
            #pragma unroll
            for (int j = 0; j < 14; ++j) {
                acc2[j] = fma2((v2f){row[j],     row[j]},     wp[0], acc2[j]);
                acc2[j] = fma2((v2f){row[j + 1], row[j + 1]}, wp[1], acc2[j]);
                acc2[j] = fma2((v2f){row[j + 2], row[j + 2]}, wp[2], acc2[j]);
                acc2[j] = fma2((v2f){row[j + 3], row[j + 3]}, wp[3], acc2[j]);
                acc2[j] = fma2((v2f){row[j + 4], row[j + 4]}, wp[4], acc2[j]);
            }
            #pragma unroll
            for (int v = 0; v < 5; ++v) whi[v] = wlo[v];
        }
        const float b = c1b_s[c];
        h16* o = s2g + (size_t)(img0 + img) * 1176 + c * 196 + i * 14 + 7 * h;
        #pragma unroll
        for (int j = 0; j < 7; ++j) {
            float t00 = fast_tanh(acc2[2 * j].x     + b);
            float t01 = fast_tanh(acc2[2 * j + 1].x + b);
            float t10 = fast_tanh(acc2[2 * j].y     + b);
            float t11 = fast_tanh(acc2[2 * j + 1].y + b);
            o[j] = (h16)(0.25f * (t00 + t01 + t10 + t11));
        }
    }
}

// ============================ K2: C3 MFMA + tanh + pool ============================
// 16 img/block, grid B/16. Stages s2 channel-interleaved [img][pos196][c8],
// builds dense B-panel (3584 h16 = 7 chunks x 512) from sparse tables,
// 7 MFMAs/position (round-6 verified), writes s4 f32 [img][400] to ws.
#define S2IMGH 1576              // halves per image (197 chunks * 8)
#define C3B_HALVES 3584          // 7 chunks x 512 h16  (round-7 bug: was 1792)

__device__ __constant__ int C3_INV[16][6] = {
    {0,1,2,-1,-1,-1},{-1,0,1,2,-1,-1},{-1,-1,0,1,2,-1},{-1,-1,-1,0,1,2},
    {0,-1,-1,-1,1,2},{0,1,-1,-1,-1,2},
    {0,1,2,3,-1,-1},{-1,0,1,2,3,-1},{-1,-1,0,1,2,3},{0,-1,-1,1,2,3},
    {0,1,-1,-1,2,3},{0,1,2,-1,-1,3},{0,1,-1,2,3,-1},{-1,0,1,-1,2,3},
    {0,-1,1,2,-1,3},
    {0,1,2,3,4,5}
};

#define K2_SMEM_BYTES (16 * S2IMGH * 2 + C3B_HALVES * 2 + 64)   // 57,664 B

__global__ __launch_bounds__(256) void k_c3(
    const h16* __restrict__ s2g,
    const float* __restrict__ c3_w3, const float* __restrict__ c3_b3,
    const float* __restrict__ c3_w4, const float* __restrict__ c3_b4,
    const float* __restrict__ c3_w6, const float* __restrict__ c3_b6,
    float* __restrict__ s4g, int B)
{
    __shared__ __align__(16) char smem[K2_SMEM_BYTES];
    h16*   s2i   = (h16*)smem;                              // [16][1576]
    h16*   c3Bh  = (h16*)(smem + 16 * S2IMGH * 2);          // 3584 h16
    float* c3b_s = (float*)(smem + 16 * S2IMGH * 2 + C3B_HALVES * 2);  // 16

    const int tid  = threadIdx.x;
    const int img0 = blockIdx.x * 16;
    const int nimg = min(16, B - img0);
    if (nimg <= 0) return;

    // zero s2i (channels 6/7 + pad must not be garbage: garbage*0 can be NaN)
    {
        float4 z = {0.f, 0.f, 0.f, 0.f};
        float4* zp = (float4*)s2i;
        for (int i = tid; i < 16 * S2IMGH / 8; i += 256) zp[i] = z;
    }
    __syncthreads();

    // stage s2 with channel interleave: read h16 pairs coalesced, 2 LDS b16 writes
    {
        const int nh2 = nimg * 588;   // pair units (1176/2 per img)
        for (int idx = tid; idx < nh2; idx += 256) {
            int img = idx / 588, ii = idx % 588;
            int c = ii / 98, p2 = (ii % 98) * 2;
            const h16* g = s2g + (size_t)(img0 + img) * 1176 + c * 196 + p2;
            h16 v0 = g[0], v1 = g[1];
            s2i[img * S2IMGH + p2 * 8 + c]       = v0;
            s2i[img * S2IMGH + (p2 + 1) * 8 + c] = v1;
        }
    }
    // build dense B panel: e = t*512 + lane*8 + c ; lane: n=map, chunk
    #pragma unroll
    for (int u = 0; u < 14; ++u) {            // 14 x 256 = 3584 entries
        const int e = tid + 256 * u;
        const int t = e >> 9, rem = e & 511, L = rem >> 3, c = rem & 7;
        const int n = L & 15, chunk = L >> 4;
        int dr, dc; bool valid = true;
        if (t <= 4)      { dr = chunk; dc = t; }
        else if (t == 5) { dr = 4; dc = chunk; }
        else             { dr = 4; dc = 4; valid = (chunk == 0); }
        float val = 0.0f;
        if (valid && c < 6) {
            const int cc = C3_INV[n][c];
            if (cc >= 0) {
                const int off = dr * 5 + dc;
                if (n < 6)       val = c3_w3[(n * 3 + cc) * 25 + off];
                else if (n < 15) val = c3_w4[((n - 6) * 4 + cc) * 25 + off];
                else             val = c3_w6[cc * 25 + off];
            }
        }
        c3Bh[e] = (h16)val;
    }
    if (tid < 6)        c3b_s[tid] = c3_b3[tid];
    else if (tid < 15)  c3b_s[tid] = c3_b4[tid - 6];
    else if (tid == 15) c3b_s[15]  = c3_b6[0];
    __syncthreads();

    // MFMA phase (round-6 verified layout), A: m=lane&15 -> image
    {
        const int lane = tid & 63, wv = tid >> 6;
        const int nloc = lane & 15, q4 = lane >> 4;
        half8 bf[7];
        #pragma unroll
        for (int t = 0; t < 7; ++t)
            bf[t] = *(const half8*)(c3Bh + t * 512 + lane * 8);
        const float bias = c3b_s[nloc];
        const int abase = nloc * S2IMGH;
        for (int q = wv; q < 25; q += 4) {
            const int pr = q / 5, pc = q % 5;
            f32x4 acc[2][2];
            #pragma unroll
            for (int a = 0; a < 2; ++a)
                #pragma unroll
                for (int b2 = 0; b2 < 2; ++b2)
                    acc[a][b2] = (f32x4){0.f, 0.f, 0.f, 0.f};
            #pragma unroll
            for (int a = 0; a < 2; ++a) {
                #pragma unroll
                for (int b2 = 0; b2 < 2; ++b2) {
                    const int r = 2 * pr + a, col = 2 * pc + b2;
                    #pragma unroll
                    for (int t = 0; t < 5; ++t) {
                        half8 A = *(const half8*)(s2i + abase + ((r + q4) * 14 + col + t) * 8);
                        acc[a][b2] = __builtin_amdgcn_mfma_f32_16x16x32_f16(A, bf[t], acc[a][b2], 0, 0, 0);
                    }
                    half8 A5 = *(const half8*)(s2i + abase + ((r + 4) * 14 + col + q4) * 8);
                    acc[a][b2] = __builtin_amdgcn_mfma_f32_16x16x32_f16(A5, bf[5], acc[a][b2], 0, 0, 0);
                    half8 A6 = *(const half8*)(s2i + abase + ((r + 4) * 14 + col + 4) * 8);
                    acc[a][b2] = __builtin_amdgcn_mfma_f32_16x16x32_f16(A6, bf[6], acc[a][b2], 0, 0, 0);
                }
            }
            const int pos = pr * 5 + pc;
            #pragma unroll
            for (int rr = 0; rr < 4; ++rr) {
                const int img = q4 * 4 + rr;       // C/D: row=(lane>>4)*4+reg
                if (img < nimg) {
                    float s = fast_tanh(acc[0][0][rr] + bias) + fast_tanh(acc[0][1][rr] + bias)
                            + fast_tanh(acc[1][0][rr] + bias) + fast_tanh(acc[1][1][rr] + bias);
                    s4g[(size_t)(img0 + img) * 400 + nloc * 25 + pos] = 0.25f * s;
                }
            }
        }
    }
}

// ============================ K3: C5 + F6 + output ============================
// 16 img/block, grid B/16. Weight-stationary FC: thread owns (2 outputs x 4 imgs)
// for C5; s4/c5o/f6 live in LDS (broadcast reads). LDS 38.7 KB.
#define K3_S4   0                         // 16*400 f32
#define K3_C5O  (16 * 400)                // 16*120 f32
#define K3_F6   (K3_C5O + 16 * 120)      // 16*84 f32
#define K3_SMEM (K3_F6 + 16 * 84)        // 9664 f32 = 38,656 B

__global__ __launch_bounds__(256) void k_tail(
    const float* __restrict__ s4g,
    const float* __restrict__ c5_w, const float* __restrict__ c5_b,
    const float* __restrict__ l1_w, const float* __restrict__ l1_b,
    const float* __restrict__ l2_w, const float* __restrict__ l2_b,
    float* __restrict__ out, int B)
{
    __shared__ __align__(16) float smem[K3_SMEM];
    float* s4l  = smem + K3_S4;
    float* c5ol = smem + K3_C5O;
    float* f6l  = smem + K3_F6;

    const int tid  = threadIdx.x;
    const int img0 = blockIdx.x * 16;
    const int nimg = min(16, B - img0);
    if (nimg <= 0) return;

    // stage s4 (zero-fill missing imgs to keep math NaN-free)
    {
        const float4* g = (const float4*)(s4g + (size_t)img0 * 400);
        float4* l = (float4*)s4l;
        const int n4 = nimg * 100;
        for (int i = tid; i < 1600; i += 256)
            l[i] = (i < n4) ? g[i] : (float4){0.f, 0.f, 0.f, 0.f};
    }
    __syncthreads();

    // C5: thread = (op in [0,60), g in [0,4)): outputs 2op,2op+1; imgs 4g..4g+3
    if (tid < 240) {
        const int op = tid % 60, g = tid / 60;
        const int o0 = op * 2;
        const float4* wa = (const float4*)(c5_w + (size_t)o0 * 400);
        const float4* wb = (const float4*)(c5_w + (size_t)o0 * 400 + 400);
        v2f acc[4];
        #pragma unroll
        for (int m = 0; m < 4; ++m) acc[m] = (v2f){0.f, 0.f};
        for (int k = 0; k < 100; ++k) {
            float4 u = wa[k];
            float4 v = wb[k];
            #pragma unroll
            for (int m = 0; m < 4; ++m) {
                float4 s = *(const float4*)(s4l + (g * 4 + m) * 400 + 4 * k);
                acc[m] = fma2((v2f){s.x, s.x}, (v2f){u.x, v.x}, acc[m]);
                acc[m] = fma2((v2f){s.y, s.y}, (v2f){u.y, v.y}, acc[m]);
                acc[m] = fma2((v2f){s.z, s.z}, (v2f){u.z, v.z}, acc[m]);
                acc[m] = fma2((v2f){s.w, s.w}, (v2f){u.w, v.w}, acc[m]);
            }
        }
        const float b0 = c5_b[o0], b1 = c5_b[o0 + 1];
        #pragma unroll
        for (int m = 0; m < 4; ++m) {
            const int img = g * 4 + m;
            c5ol[img * 120 + o0]     = fast_tanh(acc[m].x + b0);
            c5ol[img * 120 + o0 + 1] = fast_tanh(acc[m].y + b1);
        }
    }
    __syncthreads();

    // F6: thread = (o in [0,84), g in [0,3)): imgs g, g+3, ...
    if (tid < 252) {
        const int o = tid % 84, g = tid / 84;
        const float4* wv = (const float4*)(l1_w + o * 120);
        float acc[6];
        #pragma unroll
        for (int j = 0; j < 6; ++j) acc[j] = 0.f;
        for (int k = 0; k < 30; ++k) {
            float4 u = wv[k];
            #pragma unroll
            for (int j = 0; j < 6; ++j) {
                const int img = g + 3 * j;
                if (img < 16) {
                    float4 s = *(const float4*)(c5ol + img * 120 + 4 * k);
                    acc[j] = fmaf(s.x, u.x, fmaf(s.y, u.y, fmaf(s.z, u.z, fmaf(s.w, u.w, acc[j]))));
                }
            }
        }
        const float b = l1_b[o];
        #pragma unroll
        for (int j = 0; j < 6; ++j) {
            const int img = g + 3 * j;
            if (img < 16) f6l[img * 84 + o] = fast_tanh(acc[j] + b);
        }
    }
    __syncthreads();

    // out: FC 84 -> 10
    if (tid < 160) {
        const int img = tid / 10, o = tid % 10;
        if (img < nimg) {
            const float4* wv = (const float4*)(l2_w + o * 84);
            const float4* fv = (const float4*)(f6l + img * 84);
            v2f a2 = (v2f){0.f, 0.f};
            #pragma unroll
            for (int k = 0; k < 21; ++k) {
                float4 u = wv[k];
                float4 s = fv[k];
                a2 = fma2((v2f){s.x, s.y}, (v2f){u.x, u.y}, a2);
                a2 = fma2((v2f){s.z, s.w}, (v2f){u.z, u.w}, a2);
            }
            out[(size_t)(img0 + img) * 10 + o] = a2.x + a2.y + l2_b[o];
        }
    }
}

extern "C" void kernel_launch(void* const* d_in, const int* in_sizes, int n_in,
                              void* d_out, int out_size, void* d_ws, size_t ws_size,
                              hipStream_t stream) {
    const float* x     = (const float*)d_in[0];
    const float* c1_w  = (const float*)d_in[1];
    const float* c1_b  = (const float*)d_in[2];
    const float* c3_w3 = (const float*)d_in[3];
    const float* c3_b3 = (const float*)d_in[4];
    const float* c3_w4 = (const float*)d_in[5];
    const float* c3_b4 = (const float*)d_in[6];
    const float* c3_w6 = (const float*)d_in[7];
    const float* c3_b6 = (const float*)d_in[8];
    const float* c5_w  = (const float*)d_in[9];
    const float* c5_b  = (const float*)d_in[10];
    const float* l1_w  = (const float*)d_in[11];
    const float* l1_b  = (const float*)d_in[12];
    const float* l2_w  = (const float*)d_in[13];
    const float* l2_b  = (const float*)d_in[14];
    float* out = (float*)d_out;

    const int B = in_sizes[0] / 1024;   // [B,1,32,32]

    // ws layout: s2 f16 [B][1176] | s4 f32 [B][400]   (~32.4 MB at B=8192)
    h16*   s2g = (h16*)d_ws;
    float* s4g = (float*)((char*)d_ws + (size_t)B * 1176 * 2);

    k_c1<<<(B + K1_IMG - 1) / K1_IMG, 256, 0, stream>>>(x, c1_w, c1_b, s2g, B);
    k_c3<<<(B + 15) / 16, 256, 0, stream>>>(s2g, c3_w3, c3_b3, c3_w4, c3_b4,
                                            c3_w6, c3_b6, s4g, B);
    k_tail<<<(B + 15) / 16, 256, 0, stream>>>(s4g, c5_w, c5_b, l1_w, l1_b,
                                              l2_w, l2_b, out, B);
}

// Round 9
// 182.472 us; speedup vs baseline: 2.0887x; 1.2156x over previous
//
#include <hip/hip_runtime.h>

typedef float v2f   __attribute__((ext_vector_type(2)));
typedef float f32x4 __attribute__((ext_vector_type(4)));
typedef _Float16 h16;
typedef h16 half8 __attribute__((ext_vector_type(8)));

__device__ __forceinline__ float fast_tanh(float x) {
    float e = __expf(2.0f * x);
    return fmaf(-2.0f, __builtin_amdgcn_rcpf(e + 1.0f), 1.0f);
}
__device__ __forceinline__ v2f fma2(v2f a, v2f b, v2f c) {
    return __builtin_elementwise_fma(a, b, c);
}
__device__ __forceinline__ half8 cvt8(float4 u0, float4 u1) {
    return (half8){(h16)u0.x,(h16)u0.y,(h16)u0.z,(h16)u0.w,
                   (h16)u1.x,(h16)u1.y,(h16)u1.z,(h16)u1.w};
}

// ============================ K1: C1 + tanh + pool ============================
// (unchanged from round 8) 4 img/block; writes s2 f16 c-major [img][c][196].
#define K1_IMG 4
#define XSTR  34
#define XIMG  (32 * XSTR)
#define K1_SMEM (K1_IMG * XIMG + 192 + 8)

__global__ __launch_bounds__(256) void k_c1(
    const float* __restrict__ x, const float* __restrict__ c1_w,
    const float* __restrict__ c1_b, h16* __restrict__ s2g, int B)
{
    __shared__ __align__(16) float smem[K1_SMEM];
    float* x_s   = smem;
    float* c1w_s = smem + K1_IMG * XIMG;
    float* c1b_s = c1w_s + 192;

    const int tid  = threadIdx.x;
    const int img0 = blockIdx.x * K1_IMG;
    const int nimg = min(K1_IMG, B - img0);
    if (nimg <= 0) return;

    if (tid < 192) {
        int c = tid >> 5, r = tid & 31;
        int row = r / 6, v = r % 6;
        c1w_s[tid] = (row < 5 && v < 5) ? c1_w[c * 25 + row * 5 + v] : 0.0f;
    }
    if (tid < 6) c1b_s[tid] = c1_b[tid];

    {
        const float4* xg = (const float4*)(x + (size_t)img0 * 1024);
        const int n4 = nimg * 256;
        for (int i = tid; i < n4; i += 256) {
            float4 v = xg[i];
            int img = i >> 8, q = i & 255;
            int row = q >> 3, col4 = (q & 7) << 2;
            float* p = x_s + img * XIMG + row * XSTR + col4;
            *(float2*)(p)     = (float2){v.x, v.y};
            *(float2*)(p + 2) = (float2){v.z, v.w};
        }
    }
    __syncthreads();

    for (int it = tid; it < nimg * 168; it += 256) {
        int h   = it & 1;
        int t2  = it >> 1;
        int i   = t2 % 14;
        int t3  = t2 / 14;
        int c   = t3 % 6;
        int img = t3 / 6;
        const float* xb = x_s + img * XIMG + 14 * h;
        const float* wb = c1w_s + c * 32;
        v2f acc2[14];
        #pragma unroll
        for (int j = 0; j < 14; ++j) acc2[j] = (v2f){0.0f, 0.0f};
        float wlo[5], whi[5];
        #pragma unroll
        for (int v = 0; v < 5; ++v) whi[v] = 0.0f;
        #pragma unroll
        for (int xr = 0; xr < 6; ++xr) {
            if (xr <= 4) {
                float2 w0 = *(const float2*)(wb + xr * 6);
                float2 w1 = *(const float2*)(wb + xr * 6 + 2);
                float2 w2 = *(const float2*)(wb + xr * 6 + 4);
                wlo[0] = w0.x; wlo[1] = w0.y; wlo[2] = w1.x; wlo[3] = w1.y; wlo[4] = w2.x;
            } else {
                #pragma unroll
                for (int v = 0; v < 5; ++v) wlo[v] = 0.0f;
            }
            float row[18];
            const float* rp = xb + (2 * i + xr) * XSTR;
            #pragma unroll
            for (int k = 0; k < 9; ++k) {
                float2 t = *(const float2*)(rp + 2 * k);
                row[2 * k] = t.x; row[2 * k + 1] = t.y;
            }
            v2f wp[5];
            #pragma unroll
            for (int v = 0; v < 5; ++v) wp[v] = (v2f){wlo[v], whi[v]};
            #pragma unroll
            for (int j = 0; j < 14; ++j) {
                acc2[j] = fma2((v2f){row[j],     row[j]},     wp[0], acc2[j]);
                acc2[j] = fma2((v2f){row[j + 1], row[j + 1]}, wp[1], acc2[j]);
                acc2[j] = fma2((v2f){row[j + 2], row[j + 2]}, wp[2], acc2[j]);
                acc2[j] = fma2((v2f){row[j + 3], row[j + 3]}, wp[3], acc2[j]);
                acc2[j] = fma2((v2f){row[j + 4], row[j + 4]}, wp[4], acc2[j]);
            }
            #pragma unroll
            for (int v = 0; v < 5; ++v) whi[v] = wlo[v];
        }
        const float b = c1b_s[c];
        h16* o = s2g + (size_t)(img0 + img) * 1176 + c * 196 + i * 14 + 7 * h;
        #pragma unroll
        for (int j = 0; j < 7; ++j) {
            float t00 = fast_tanh(acc2[2 * j].x     + b);
            float t01 = fast_tanh(acc2[2 * j + 1].x + b);
            float t10 = fast_tanh(acc2[2 * j].y     + b);
            float t11 = fast_tanh(acc2[2 * j + 1].y + b);
            o[j] = (h16)(0.25f * (t00 + t01 + t10 + t11));
        }
    }
}

// ============================ K2: C3 MFMA + tanh + pool ============================
// (round-8 proven; one change: writes s4 as f16)
#define S2IMGH 1576
#define C3B_HALVES 3584

__device__ __constant__ int C3_INV[16][6] = {
    {0,1,2,-1,-1,-1},{-1,0,1,2,-1,-1},{-1,-1,0,1,2,-1},{-1,-1,-1,0,1,2},
    {0,-1,-1,-1,1,2},{0,1,-1,-1,-1,2},
    {0,1,2,3,-1,-1},{-1,0,1,2,3,-1},{-1,-1,0,1,2,3},{0,-1,-1,1,2,3},
    {0,1,-1,-1,2,3},{0,1,2,-1,-1,3},{0,1,-1,2,3,-1},{-1,0,1,-1,2,3},
    {0,-1,1,2,-1,3},
    {0,1,2,3,4,5}
};

#define K2_SMEM_BYTES (16 * S2IMGH * 2 + C3B_HALVES * 2 + 64)

__global__ __launch_bounds__(256) void k_c3(
    const h16* __restrict__ s2g,
    const float* __restrict__ c3_w3, const float* __restrict__ c3_b3,
    const float* __restrict__ c3_w4, const float* __restrict__ c3_b4,
    const float* __restrict__ c3_w6, const float* __restrict__ c3_b6,
    h16* __restrict__ s4g, int B)
{
    __shared__ __align__(16) char smem[K2_SMEM_BYTES];
    h16*   s2i   = (h16*)smem;
    h16*   c3Bh  = (h16*)(smem + 16 * S2IMGH * 2);
    float* c3b_s = (float*)(smem + 16 * S2IMGH * 2 + C3B_HALVES * 2);

    const int tid  = threadIdx.x;
    const int img0 = blockIdx.x * 16;
    const int nimg = min(16, B - img0);
    if (nimg <= 0) return;

    {
        float4 z = {0.f, 0.f, 0.f, 0.f};
        float4* zp = (float4*)s2i;
        for (int i = tid; i < 16 * S2IMGH / 8; i += 256) zp[i] = z;
    }
    __syncthreads();

    {
        const int nh2 = nimg * 588;
        for (int idx = tid; idx < nh2; idx += 256) {
            int img = idx / 588, ii = idx % 588;
            int c = ii / 98, p2 = (ii % 98) * 2;
            const h16* g = s2g + (size_t)(img0 + img) * 1176 + c * 196 + p2;
            h16 v0 = g[0], v1 = g[1];
            s2i[img * S2IMGH + p2 * 8 + c]       = v0;
            s2i[img * S2IMGH + (p2 + 1) * 8 + c] = v1;
        }
    }
    #pragma unroll
    for (int u = 0; u < 14; ++u) {
        const int e = tid + 256 * u;
        const int t = e >> 9, rem = e & 511, L = rem >> 3, c = rem & 7;
        const int n = L & 15, chunk = L >> 4;
        int dr, dc; bool valid = true;
        if (t <= 4)      { dr = chunk; dc = t; }
        else if (t == 5) { dr = 4; dc = chunk; }
        else             { dr = 4; dc = 4; valid = (chunk == 0); }
        float val = 0.0f;
        if (valid && c < 6) {
            const int cc = C3_INV[n][c];
            if (cc >= 0) {
                const int off = dr * 5 + dc;
                if (n < 6)       val = c3_w3[(n * 3 + cc) * 25 + off];
                else if (n < 15) val = c3_w4[((n - 6) * 4 + cc) * 25 + off];
                else             val = c3_w6[cc * 25 + off];
            }
        }
        c3Bh[e] = (h16)val;
    }
    if (tid < 6)        c3b_s[tid] = c3_b3[tid];
    else if (tid < 15)  c3b_s[tid] = c3_b4[tid - 6];
    else if (tid == 15) c3b_s[15]  = c3_b6[0];
    __syncthreads();

    {
        const int lane = tid & 63, wv = tid >> 6;
        const int nloc = lane & 15, q4 = lane >> 4;
        half8 bf[7];
        #pragma unroll
        for (int t = 0; t < 7; ++t)
            bf[t] = *(const half8*)(c3Bh + t * 512 + lane * 8);
        const float bias = c3b_s[nloc];
        const int abase = nloc * S2IMGH;
        for (int q = wv; q < 25; q += 4) {
            const int pr = q / 5, pc = q % 5;
            f32x4 acc[2][2];
            #pragma unroll
            for (int a = 0; a < 2; ++a)
                #pragma unroll
                for (int b2 = 0; b2 < 2; ++b2)
                    acc[a][b2] = (f32x4){0.f, 0.f, 0.f, 0.f};
            #pragma unroll
            for (int a = 0; a < 2; ++a) {
                #pragma unroll
                for (int b2 = 0; b2 < 2; ++b2) {
                    const int r = 2 * pr + a, col = 2 * pc + b2;
                    #pragma unroll
                    for (int t = 0; t < 5; ++t) {
                        half8 A = *(const half8*)(s2i + abase + ((r + q4) * 14 + col + t) * 8);
                        acc[a][b2] = __builtin_amdgcn_mfma_f32_16x16x32_f16(A, bf[t], acc[a][b2], 0, 0, 0);
                    }
                    half8 A5 = *(const half8*)(s2i + abase + ((r + 4) * 14 + col + q4) * 8);
                    acc[a][b2] = __builtin_amdgcn_mfma_f32_16x16x32_f16(A5, bf[5], acc[a][b2], 0, 0, 0);
                    half8 A6 = *(const half8*)(s2i + abase + ((r + 4) * 14 + col + 4) * 8);
                    acc[a][b2] = __builtin_amdgcn_mfma_f32_16x16x32_f16(A6, bf[6], acc[a][b2], 0, 0, 0);
                }
            }
            const int pos = pr * 5 + pc;
            #pragma unroll
            for (int rr = 0; rr < 4; ++rr) {
                const int img = q4 * 4 + rr;
                if (img < nimg) {
                    float s = fast_tanh(acc[0][0][rr] + bias) + fast_tanh(acc[0][1][rr] + bias)
                            + fast_tanh(acc[1][0][rr] + bias) + fast_tanh(acc[1][1][rr] + bias);
                    s4g[(size_t)(img0 + img) * 400 + nloc * 25 + pos] = (h16)(0.25f * s);
                }
            }
        }
    }
}

// ============================ K3: tail as 3 chained MFMA GEMMs ============================
// 16 img/block, grid B/16. C5: M16 N128(120) K416(400); F6: M16 N96(84) K128(120);
// OUT: M16 N16(10) K96(84). B-fragments converted from global f32 (L2-resident,
// no staging barriers). Activation strides 424/136/104 halves: rows 16B-aligned,
// <=2-way LDS banks. 3 barriers total.
#define KT_IMG   16
#define S4L_STR  424
#define C5O_STR  136
#define F6L_STR  104
#define KT_S4L   0
#define KT_C5OL  (KT_IMG * S4L_STR * 2)                  // 13568
#define KT_F6L   (KT_C5OL + KT_IMG * C5O_STR * 2)        // 17920
#define KT_BIAS  (KT_F6L + KT_IMG * F6L_STR * 2)         // 21248
#define KT_SMEM  (KT_BIAS + 240 * 4)                     // 22208 B -> 7 blocks/CU cap

__global__ __launch_bounds__(256) void k_tail(
    const h16* __restrict__ s4g,
    const float* __restrict__ c5_w, const float* __restrict__ c5_b,
    const float* __restrict__ l1_w, const float* __restrict__ l1_b,
    const float* __restrict__ l2_w, const float* __restrict__ l2_b,
    float* __restrict__ out, int B)
{
    __shared__ __align__(16) char smem[KT_SMEM];
    h16*   s4l   = (h16*)(smem + KT_S4L);
    h16*   c5ol  = (h16*)(smem + KT_C5OL);
    h16*   f6l   = (h16*)(smem + KT_F6L);
    float* c5b_s = (float*)(smem + KT_BIAS);   // 128
    float* l1b_s = c5b_s + 128;                // 96
    float* l2b_s = l1b_s + 96;                 // 16

    const int tid  = threadIdx.x;
    const int img0 = blockIdx.x * KT_IMG;
    const int nimg = min(KT_IMG, B - img0);
    if (nimg <= 0) return;

    if (tid < 128)      c5b_s[tid] = (tid < 120) ? c5_b[tid] : 0.f;
    else if (tid < 224) { int i = tid - 128; l1b_s[i] = (i < 84) ? l1_b[i] : 0.f; }
    else if (tid < 240) { int i = tid - 224; l2b_s[i] = (i < 10) ? l2_b[i] : 0.f; }

    // stage s4 f16 -> s4l [16][424] (zero pad cols 400.. and missing imgs)
    {
        const half8 z = {(h16)0,(h16)0,(h16)0,(h16)0,(h16)0,(h16)0,(h16)0,(h16)0};
        for (int i = tid; i < KT_IMG * 53; i += 256) {
            int img = i / 53, cc = i % 53;
            half8 v = z;
            if (img < nimg && cc < 50)
                v = *(const half8*)(s4g + (size_t)(img0 + img) * 400 + cc * 8);
            *(half8*)(s4l + img * S4L_STR + cc * 8) = v;
        }
    }
    __syncthreads();

    const int lane = tid & 63, wv = tid >> 6;
    const int nloc = lane & 15, q4 = lane >> 4;
    const half8 z8 = {(h16)0,(h16)0,(h16)0,(h16)0,(h16)0,(h16)0,(h16)0,(h16)0};

    // ===== C5: wave w owns n-tiles {2w, 2w+1} =====
    {
        const int nb = wv * 2;
        f32x4 acc[2];
        acc[0] = (f32x4){0.f,0.f,0.f,0.f};
        acc[1] = (f32x4){0.f,0.f,0.f,0.f};
        for (int ks = 0; ks < 13; ++ks) {
            const int ka = ks * 32 + q4 * 8;
            half8 A = *(const half8*)(s4l + nloc * S4L_STR + ka);
            #pragma unroll
            for (int t = 0; t < 2; ++t) {
                const int n = (nb + t) * 16 + nloc;
                half8 Bf = z8;
                if (n < 120 && ka < 400) {
                    float4 u0 = *(const float4*)(c5_w + n * 400 + ka);
                    float4 u1 = *(const float4*)(c5_w + n * 400 + ka + 4);
                    Bf = cvt8(u0, u1);
                }
                acc[t] = __builtin_amdgcn_mfma_f32_16x16x32_f16(A, Bf, acc[t], 0, 0, 0);
            }
        }
        #pragma unroll
        for (int t = 0; t < 2; ++t) {
            const int o = (nb + t) * 16 + nloc;
            const float bo = c5b_s[o];
            #pragma unroll
            for (int r = 0; r < 4; ++r) {
                const int img = q4 * 4 + r;
                c5ol[img * C5O_STR + o] = (h16)fast_tanh(acc[t][r] + bo);
            }
        }
    }
    __syncthreads();

    // ===== F6: waves 0-2 own n-tiles {2w, 2w+1} of 6 =====
    if (wv < 3) {
        const int nb = wv * 2;
        f32x4 acc[2];
        acc[0] = (f32x4){0.f,0.f,0.f,0.f};
        acc[1] = (f32x4){0.f,0.f,0.f,0.f};
        for (int ks = 0; ks < 4; ++ks) {
            const int ka = ks * 32 + q4 * 8;
            half8 A = *(const half8*)(c5ol + nloc * C5O_STR + ka);
            #pragma unroll
            for (int t = 0; t < 2; ++t) {
                const int n = (nb + t) * 16 + nloc;
                half8 Bf = z8;
                if (n < 84 && ka < 120) {
                    float4 u0 = *(const float4*)(l1_w + n * 120 + ka);
                    float4 u1 = *(const float4*)(l1_w + n * 120 + ka + 4);
                    Bf = cvt8(u0, u1);
                }
                acc[t] = __builtin_amdgcn_mfma_f32_16x16x32_f16(A, Bf, acc[t], 0, 0, 0);
            }
        }
        #pragma unroll
        for (int t = 0; t < 2; ++t) {
            const int o = (nb + t) * 16 + nloc;
            const float bo = l1b_s[o];
            #pragma unroll
            for (int r = 0; r < 4; ++r) {
                const int img = q4 * 4 + r;
                f6l[img * F6L_STR + o] = (h16)fast_tanh(acc[t][r] + bo);
            }
        }
    }
    __syncthreads();

    // ===== OUT: wave 0 =====
    if (wv == 0) {
        f32x4 acc = (f32x4){0.f,0.f,0.f,0.f};
        #pragma unroll
        for (int ks = 0; ks < 3; ++ks) {
            const int ka = ks * 32 + q4 * 8;
            half8 A = *(const half8*)(f6l + nloc * F6L_STR + ka);
            half8 Bf = z8;
            #pragma unroll
            for (int i = 0; i < 8; ++i) {
                const int k = ka + i;
                if (nloc < 10 && k < 84) Bf[i] = (h16)l2_w[nloc * 84 + k];
            }
            acc = __builtin_amdgcn_mfma_f32_16x16x32_f16(A, Bf, acc, 0, 0, 0);
        }
        if (nloc < 10) {
            #pragma unroll
            for (int r = 0; r < 4; ++r) {
                const int img = q4 * 4 + r;
                if (img < nimg)
                    out[(size_t)(img0 + img) * 10 + nloc] = acc[r] + l2b_s[nloc];
            }
        }
    }
}

extern "C" void kernel_launch(void* const* d_in, const int* in_sizes, int n_in,
                              void* d_out, int out_size, void* d_ws, size_t ws_size,
                              hipStream_t stream) {
    const float* x     = (const float*)d_in[0];
    const float* c1_w  = (const float*)d_in[1];
    const float* c1_b  = (const float*)d_in[2];
    const float* c3_w3 = (const float*)d_in[3];
    const float* c3_b3 = (const float*)d_in[4];
    const float* c3_w4 = (const float*)d_in[5];
    const float* c3_b4 = (const float*)d_in[6];
    const float* c3_w6 = (const float*)d_in[7];
    const float* c3_b6 = (const float*)d_in[8];
    const float* c5_w  = (const float*)d_in[9];
    const float* c5_b  = (const float*)d_in[10];
    const float* l1_w  = (const float*)d_in[11];
    const float* l1_b  = (const float*)d_in[12];
    const float* l2_w  = (const float*)d_in[13];
    const float* l2_b  = (const float*)d_in[14];
    float* out = (float*)d_out;

    const int B = in_sizes[0] / 1024;   // [B,1,32,32]

    // ws: s2 f16 [B][1176] | s4 f16 [B][400]  (~26 MB at B=8192)
    h16* s2g = (h16*)d_ws;
    h16* s4g = (h16*)((char*)d_ws + (size_t)B * 1176 * 2);

    k_c1<<<(B + K1_IMG - 1) / K1_IMG, 256, 0, stream>>>(x, c1_w, c1_b, s2g, B);
    k_c3<<<(B + 15) / 16, 256, 0, stream>>>(s2g, c3_w3, c3_b3, c3_w4, c3_b4,
                                            c3_w6, c3_b6, s4g, B);
    k_tail<<<(B + KT_IMG - 1) / KT_IMG, 256, 0, stream>>>(s4g, c5_w, c5_b,
                                                          l1_w, l1_b, l2_w, l2_b, out, B);
}

// Round 10
// 178.617 us; speedup vs baseline: 2.1338x; 1.0216x over previous
//
#include <hip/hip_runtime.h>

typedef float v2f   __attribute__((ext_vector_type(2)));
typedef float f32x4 __attribute__((ext_vector_type(4)));
typedef _Float16 h16;
typedef h16 half8 __attribute__((ext_vector_type(8)));
typedef h16 half4 __attribute__((ext_vector_type(4)));

__device__ __forceinline__ float fast_tanh(float x) {
    float e = __expf(2.0f * x);
    return fmaf(-2.0f, __builtin_amdgcn_rcpf(e + 1.0f), 1.0f);
}
__device__ __forceinline__ half8 cvt8(float4 u0, float4 u1) {
    return (half8){(h16)u0.x,(h16)u0.y,(h16)u0.z,(h16)u0.w,
                   (h16)u1.x,(h16)u1.y,(h16)u1.z,(h16)u1.w};
}

#define S2IMGH 1576   // s2 halves per image: [196 pos + 1 pad][8 ch]

// ============================ K1: C1 via Toeplitz MFMA ============================
// 8 img/block, grid B/8. GEMM per conv-row: D[m=(img,half)][n=(map*32+j)] =
// sum_{ks<5} A_ks x B_ks, A_ks = x row (cr+ks+14*half) (raw, contiguous),
// B_ks[n][col] = w[map][ks][col-j]. Pool via tanh + rr-pair + shfl_xor(1).
// Writes s2 f16 channel-interleaved [img][pos196][c8] directly (k_c3's layout).
#define C1_IMG 8
#define XROW  40                  // halves per x row (16B-aligned rows)
#define XIMGH (32 * XROW + 8)     // 1288 halves; img stride shifts banks by 4

__global__ __launch_bounds__(256) void k_c1(
    const float* __restrict__ x, const float* __restrict__ c1_w,
    const float* __restrict__ c1_b, h16* __restrict__ s2g, int B)
{
    __shared__ __align__(16) h16 xs[C1_IMG * XIMGH];   // 20,608 B
    __shared__ float c1w_s[152];
    __shared__ float c1b_s[8];

    const int tid  = threadIdx.x;
    const int img0 = blockIdx.x * C1_IMG;
    const int nimg = min(C1_IMG, B - img0);
    if (nimg <= 0) return;

    if (tid < 150) c1w_s[tid] = c1_w[tid];
    if (tid < 6)   c1b_s[tid] = c1_b[tid];

    // stage x f32 -> f16 rows
    {
        const float4* xg = (const float4*)(x + (size_t)img0 * 1024);
        const int n4 = nimg * 256;
        for (int i = tid; i < n4; i += 256) {
            float4 v = xg[i];
            int img = i >> 8, q = i & 255;
            int row = q >> 3, col4 = (q & 7) << 2;
            *(half4*)(xs + img * XIMGH + row * XROW + col4) =
                (half4){(h16)v.x, (h16)v.y, (h16)v.z, (h16)v.w};
        }
    }
    __syncthreads();

    const int lane = tid & 63, wv = tid >> 6;
    const int nloc = lane & 15, q4 = lane >> 4;

    // ---- build Toeplitz B fragments: wave wv owns n-tiles 3wv..3wv+2 ----
    half8 bf[3][5];
    float bias[3];
    #pragma unroll
    for (int t = 0; t < 3; ++t) {
        const int tile = 3 * wv + t;
        const int map  = tile >> 1;
        const int j    = ((tile & 1) << 4) + nloc;     // n & 31
        bias[t] = c1b_s[map];
        #pragma unroll
        for (int ks = 0; ks < 5; ++ks) {
            half8 f;
            #pragma unroll
            for (int jj = 0; jj < 8; ++jj) {
                const int d = q4 * 8 + jj - j;         // col - j
                f[jj] = (d >= 0 && d < 5) ? (h16)c1w_s[map * 25 + ks * 5 + d] : (h16)0;
            }
            bf[t][ks] = f;
        }
    }

    // ---- main loop: M-row = (img = nloc>>1, half = nloc&1) ----
    const int imgL = nloc >> 1, hf = nloc & 1;
    const h16* xrow = xs + imgL * XIMGH + hf * (14 * XROW) + q4 * 8;
    half8 rf[5];
    #pragma unroll
    for (int r = 0; r < 5; ++r) rf[r] = *(const half8*)(xrow + r * XROW);

    float t0[3][4];
    for (int cr = 0; cr < 14; ++cr) {
        f32x4 acc[3];
        #pragma unroll
        for (int t = 0; t < 3; ++t) acc[t] = (f32x4){0.f, 0.f, 0.f, 0.f};
        #pragma unroll
        for (int ks = 0; ks < 5; ++ks) {
            #pragma unroll
            for (int t = 0; t < 3; ++t)
                acc[t] = __builtin_amdgcn_mfma_f32_16x16x32_f16(rf[ks], bf[t][ks], acc[t], 0, 0, 0);
        }
        if ((cr & 1) == 0) {
            #pragma unroll
            for (int t = 0; t < 3; ++t)
                #pragma unroll
                for (int r = 0; r < 4; ++r)
                    t0[t][r] = fast_tanh(acc[t][r] + bias[t]);
        } else {
            #pragma unroll
            for (int t = 0; t < 3; ++t) {
                const int tile = 3 * wv + t;
                const int jp   = (((tile & 1) << 4) + nloc) >> 1;   // j>>1
                const int map  = tile >> 1;
                #pragma unroll
                for (int r = 0; r < 4; ++r) {
                    float s = t0[t][r] + fast_tanh(acc[t][r] + bias[t]);
                    float o = 0.25f * (s + __shfl_xor(s, 1));
                    const int m = q4 * 4 + r;                 // C/D row = m
                    const int img = m >> 1, mh = m & 1;
                    const int ip  = (cr >> 1) + 7 * mh;
                    if (!(lane & 1) && jp < 14 && img < nimg)
                        s2g[(size_t)(img0 + img) * S2IMGH + (ip * 14 + jp) * 8 + map] = (h16)o;
                }
            }
        }
        if (cr < 13) {
            rf[0] = rf[1]; rf[1] = rf[2]; rf[2] = rf[3]; rf[3] = rf[4];
            rf[4] = *(const half8*)(xrow + (cr + 5) * XROW);
        }
    }
}

// ============================ K2: C3 MFMA + tanh + pool ============================
// (round-9 proven MFMA phase; staging is now a coalesced half8 copy since
// k_c1 writes the interleaved layout directly. ch6/7 garbage is finite f16
// (0xAA poison) and hits zero B-weights -> contributes exactly 0.)
#define C3B_HALVES 3584

__device__ __constant__ int C3_INV[16][6] = {
    {0,1,2,-1,-1,-1},{-1,0,1,2,-1,-1},{-1,-1,0,1,2,-1},{-1,-1,-1,0,1,2},
    {0,-1,-1,-1,1,2},{0,1,-1,-1,-1,2},
    {0,1,2,3,-1,-1},{-1,0,1,2,3,-1},{-1,-1,0,1,2,3},{0,-1,-1,1,2,3},
    {0,1,-1,-1,2,3},{0,1,2,-1,-1,3},{0,1,-1,2,3,-1},{-1,0,1,-1,2,3},
    {0,-1,1,2,-1,3},
    {0,1,2,3,4,5}
};

#define K2_SMEM_BYTES (16 * S2IMGH * 2 + C3B_HALVES * 2 + 64)

__global__ __launch_bounds__(256) void k_c3(
    const h16* __restrict__ s2g,
    const float* __restrict__ c3_w3, const float* __restrict__ c3_b3,
    const float* __restrict__ c3_w4, const float* __restrict__ c3_b4,
    const float* __restrict__ c3_w6, const float* __restrict__ c3_b6,
    h16* __restrict__ s4g, int B)
{
    __shared__ __align__(16) char smem[K2_SMEM_BYTES];
    h16*   s2i   = (h16*)smem;
    h16*   c3Bh  = (h16*)(smem + 16 * S2IMGH * 2);
    float* c3b_s = (float*)(smem + 16 * S2IMGH * 2 + C3B_HALVES * 2);

    const int tid  = threadIdx.x;
    const int img0 = blockIdx.x * 16;
    const int nimg = min(16, B - img0);
    if (nimg <= 0) return;

    // coalesced copy: 16 imgs x 197 half8 chunks
    {
        const int img = tid >> 4;
        if (img < nimg) {
            for (int c = (tid & 15); c < 197; c += 16)
                *(half8*)(s2i + img * S2IMGH + c * 8) =
                    *(const half8*)(s2g + (size_t)(img0 + img) * S2IMGH + c * 8);
        }
    }
    #pragma unroll
    for (int u = 0; u < 14; ++u) {
        const int e = tid + 256 * u;
        const int t = e >> 9, rem = e & 511, L = rem >> 3, c = rem & 7;
        const int n = L & 15, chunk = L >> 4;
        int dr, dc; bool valid = true;
        if (t <= 4)      { dr = chunk; dc = t; }
        else if (t == 5) { dr = 4; dc = chunk; }
        else             { dr = 4; dc = 4; valid = (chunk == 0); }
        float val = 0.0f;
        if (valid && c < 6) {
            const int cc = C3_INV[n][c];
            if (cc >= 0) {
                const int off = dr * 5 + dc;
                if (n < 6)       val = c3_w3[(n * 3 + cc) * 25 + off];
                else if (n < 15) val = c3_w4[((n - 6) * 4 + cc) * 25 + off];
                else             val = c3_w6[cc * 25 + off];
            }
        }
        c3Bh[e] = (h16)val;
    }
    if (tid < 6)        c3b_s[tid] = c3_b3[tid];
    else if (tid < 15)  c3b_s[tid] = c3_b4[tid - 6];
    else if (tid == 15) c3b_s[15]  = c3_b6[0];
    __syncthreads();

    {
        const int lane = tid & 63, wv = tid >> 6;
        const int nloc = lane & 15, q4 = lane >> 4;
        half8 bf[7];
        #pragma unroll
        for (int t = 0; t < 7; ++t)
            bf[t] = *(const half8*)(c3Bh + t * 512 + lane * 8);
        const float bias = c3b_s[nloc];
        const int abase = nloc * S2IMGH;
        for (int q = wv; q < 25; q += 4) {
            const int pr = q / 5, pc = q % 5;
            f32x4 acc[2][2];
            #pragma unroll
            for (int a = 0; a < 2; ++a)
                #pragma unroll
                for (int b2 = 0; b2 < 2; ++b2)
                    acc[a][b2] = (f32x4){0.f, 0.f, 0.f, 0.f};
            #pragma unroll
            for (int a = 0; a < 2; ++a) {
                #pragma unroll
                for (int b2 = 0; b2 < 2; ++b2) {
                    const int r = 2 * pr + a, col = 2 * pc + b2;
                    #pragma unroll
                    for (int t = 0; t < 5; ++t) {
                        half8 A = *(const half8*)(s2i + abase + ((r + q4) * 14 + col + t) * 8);
                        acc[a][b2] = __builtin_amdgcn_mfma_f32_16x16x32_f16(A, bf[t], acc[a][b2], 0, 0, 0);
                    }
                    half8 A5 = *(const half8*)(s2i + abase + ((r + 4) * 14 + col + q4) * 8);
                    acc[a][b2] = __builtin_amdgcn_mfma_f32_16x16x32_f16(A5, bf[5], acc[a][b2], 0, 0, 0);
                    half8 A6 = *(const half8*)(s2i + abase + ((r + 4) * 14 + col + 4) * 8);
                    acc[a][b2] = __builtin_amdgcn_mfma_f32_16x16x32_f16(A6, bf[6], acc[a][b2], 0, 0, 0);
                }
            }
            const int pos = pr * 5 + pc;
            #pragma unroll
            for (int rr = 0; rr < 4; ++rr) {
                const int img = q4 * 4 + rr;
                if (img < nimg) {
                    float s = fast_tanh(acc[0][0][rr] + bias) + fast_tanh(acc[0][1][rr] + bias)
                            + fast_tanh(acc[1][0][rr] + bias) + fast_tanh(acc[1][1][rr] + bias);
                    s4g[(size_t)(img0 + img) * 400 + nloc * 25 + pos] = (h16)(0.25f * s);
                }
            }
        }
    }
}

// ============================ K3: tail as 3 chained MFMA GEMMs ============================
// (unchanged from round 9)
#define KT_IMG   16
#define S4L_STR  424
#define C5O_STR  136
#define F6L_STR  104
#define KT_S4L   0
#define KT_C5OL  (KT_IMG * S4L_STR * 2)
#define KT_F6L   (KT_C5OL + KT_IMG * C5O_STR * 2)
#define KT_BIAS  (KT_F6L + KT_IMG * F6L_STR * 2)
#define KT_SMEM  (KT_BIAS + 240 * 4)

__global__ __launch_bounds__(256) void k_tail(
    const h16* __restrict__ s4g,
    const float* __restrict__ c5_w, const float* __restrict__ c5_b,
    const float* __restrict__ l1_w, const float* __restrict__ l1_b,
    const float* __restrict__ l2_w, const float* __restrict__ l2_b,
    float* __restrict__ out, int B)
{
    __shared__ __align__(16) char smem[KT_SMEM];
    h16*   s4l   = (h16*)(smem + KT_S4L);
    h16*   c5ol  = (h16*)(smem + KT_C5OL);
    h16*   f6l   = (h16*)(smem + KT_F6L);
    float* c5b_s = (float*)(smem + KT_BIAS);
    float* l1b_s = c5b_s + 128;
    float* l2b_s = l1b_s + 96;

    const int tid  = threadIdx.x;
    const int img0 = blockIdx.x * KT_IMG;
    const int nimg = min(KT_IMG, B - img0);
    if (nimg <= 0) return;

    if (tid < 128)      c5b_s[tid] = (tid < 120) ? c5_b[tid] : 0.f;
    else if (tid < 224) { int i = tid - 128; l1b_s[i] = (i < 84) ? l1_b[i] : 0.f; }
    else if (tid < 240) { int i = tid - 224; l2b_s[i] = (i < 10) ? l2_b[i] : 0.f; }

    {
        const half8 z = {(h16)0,(h16)0,(h16)0,(h16)0,(h16)0,(h16)0,(h16)0,(h16)0};
        for (int i = tid; i < KT_IMG * 53; i += 256) {
            int img = i / 53, cc = i % 53;
            half8 v = z;
            if (img < nimg && cc < 50)
                v = *(const half8*)(s4g + (size_t)(img0 + img) * 400 + cc * 8);
            *(half8*)(s4l + img * S4L_STR + cc * 8) = v;
        }
    }
    __syncthreads();

    const int lane = tid & 63, wv = tid >> 6;
    const int nloc = lane & 15, q4 = lane >> 4;
    const half8 z8 = {(h16)0,(h16)0,(h16)0,(h16)0,(h16)0,(h16)0,(h16)0,(h16)0};

    // ===== C5 =====
    {
        const int nb = wv * 2;
        f32x4 acc[2];
        acc[0] = (f32x4){0.f,0.f,0.f,0.f};
        acc[1] = (f32x4){0.f,0.f,0.f,0.f};
        for (int ks = 0; ks < 13; ++ks) {
            const int ka = ks * 32 + q4 * 8;
            half8 A = *(const half8*)(s4l + nloc * S4L_STR + ka);
            #pragma unroll
            for (int t = 0; t < 2; ++t) {
                const int n = (nb + t) * 16 + nloc;
                half8 Bf = z8;
                if (n < 120 && ka < 400) {
                    float4 u0 = *(const float4*)(c5_w + n * 400 + ka);
                    float4 u1 = *(const float4*)(c5_w + n * 400 + ka + 4);
                    Bf = cvt8(u0, u1);
                }
                acc[t] = __builtin_amdgcn_mfma_f32_16x16x32_f16(A, Bf, acc[t], 0, 0, 0);
            }
        }
        #pragma unroll
        for (int t = 0; t < 2; ++t) {
            const int o = (nb + t) * 16 + nloc;
            const float bo = c5b_s[o];
            #pragma unroll
            for (int r = 0; r < 4; ++r) {
                const int img = q4 * 4 + r;
                c5ol[img * C5O_STR + o] = (h16)fast_tanh(acc[t][r] + bo);
            }
        }
    }
    __syncthreads();

    // ===== F6 =====
    if (wv < 3) {
        const int nb = wv * 2;
        f32x4 acc[2];
        acc[0] = (f32x4){0.f,0.f,0.f,0.f};
        acc[1] = (f32x4){0.f,0.f,0.f,0.f};
        for (int ks = 0; ks < 4; ++ks) {
            const int ka = ks * 32 + q4 * 8;
            half8 A = *(const half8*)(c5ol + nloc * C5O_STR + ka);
            #pragma unroll
            for (int t = 0; t < 2; ++t) {
                const int n = (nb + t) * 16 + nloc;
                half8 Bf = z8;
                if (n < 84 && ka < 120) {
                    float4 u0 = *(const float4*)(l1_w + n * 120 + ka);
                    float4 u1 = *(const float4*)(l1_w + n * 120 + ka + 4);
                    Bf = cvt8(u0, u1);
                }
                acc[t] = __builtin_amdgcn_mfma_f32_16x16x32_f16(A, Bf, acc[t], 0, 0, 0);
            }
        }
        #pragma unroll
        for (int t = 0; t < 2; ++t) {
            const int o = (nb + t) * 16 + nloc;
            const float bo = l1b_s[o];
            #pragma unroll
            for (int r = 0; r < 4; ++r) {
                const int img = q4 * 4 + r;
                f6l[img * F6L_STR + o] = (h16)fast_tanh(acc[t][r] + bo);
            }
        }
    }
    __syncthreads();

    // ===== OUT =====
    if (wv == 0) {
        f32x4 acc = (f32x4){0.f,0.f,0.f,0.f};
        #pragma unroll
        for (int ks = 0; ks < 3; ++ks) {
            const int ka = ks * 32 + q4 * 8;
            half8 A = *(const half8*)(f6l + nloc * F6L_STR + ka);
            half8 Bf = z8;
            #pragma unroll
            for (int i = 0; i < 8; ++i) {
                const int k = ka + i;
                if (nloc < 10 && k < 84) Bf[i] = (h16)l2_w[nloc * 84 + k];
            }
            acc = __builtin_amdgcn_mfma_f32_16x16x32_f16(A, Bf, acc, 0, 0, 0);
        }
        if (nloc < 10) {
            #pragma unroll
            for (int r = 0; r < 4; ++r) {
                const int img = q4 * 4 + r;
                if (img < nimg)
                    out[(size_t)(img0 + img) * 10 + nloc] = acc[r] + l2b_s[nloc];
            }
        }
    }
}

extern "C" void kernel_launch(void* const* d_in, const int* in_sizes, int n_in,
                              void* d_out, int out_size, void* d_ws, size_t ws_size,
                              hipStream_t stream) {
    const float* x     = (const float*)d_in[0];
    const float* c1_w  = (const float*)d_in[1];
    const float* c1_b  = (const float*)d_in[2];
    const float* c3_w3 = (const float*)d_in[3];
    const float* c3_b3 = (const float*)d_in[4];
    const float* c3_w4 = (const float*)d_in[5];
    const float* c3_b4 = (const float*)d_in[6];
    const float* c3_w6 = (const float*)d_in[7];
    const float* c3_b6 = (const float*)d_in[8];
    const float* c5_w  = (const float*)d_in[9];
    const float* c5_b  = (const float*)d_in[10];
    const float* l1_w  = (const float*)d_in[11];
    const float* l1_b  = (const float*)d_in[12];
    const float* l2_w  = (const float*)d_in[13];
    const float* l2_b  = (const float*)d_in[14];
    float* out = (float*)d_out;

    const int B = in_sizes[0] / 1024;   // [B,1,32,32]

    // ws: s2 f16 interleaved [B][1576] | s4 f16 [B][400]  (~32.4 MB at B=8192)
    h16* s2g = (h16*)d_ws;
    h16* s4g = (h16*)((char*)d_ws + (size_t)B * S2IMGH * 2);

    k_c1<<<(B + C1_IMG - 1) / C1_IMG, 256, 0, stream>>>(x, c1_w, c1_b, s2g, B);
    k_c3<<<(B + 15) / 16, 256, 0, stream>>>(s2g, c3_w3, c3_b3, c3_w4, c3_b4,
                                            c3_w6, c3_b6, s4g, B);
    k_tail<<<(B + KT_IMG - 1) / KT_IMG, 256, 0, stream>>>(s4g, c5_w, c5_b,
                                                          l1_w, l1_b, l2_w, l2_b, out, B);
}